// Round 5
// baseline (172.168 us; speedup 1.0000x reference)
//
#include <hip/hip_runtime.h>
#include <hip/hip_fp16.h>
#include <math.h>

typedef _Float16 half8  __attribute__((ext_vector_type(8)));
typedef _Float16 half2v __attribute__((ext_vector_type(2)));
typedef float   floatx4 __attribute__((ext_vector_type(4)));

#define ROWS   16384
#define DIM    128
#define KCODES 8192
#define NSPLIT 16
#define MTILE  512
#define NT     64
#define NCHUNK ((KCODES / NSPLIT) / NT)   // 8
#define LOSS_SCALE (1.0f / ((float)ROWS * (float)DIM))

__device__ __forceinline__ void async_copy16(const _Float16* src, _Float16* dst_lds) {
  __builtin_amdgcn_global_load_lds((const __attribute__((address_space(1))) void*)src,
                                   (__attribute__((address_space(3))) void*)dst_lds,
                                   16, 0, 0);
}

// ---------------- kernel 1: codebook prep (fp16 hi/lo split + (-e2/2)) ----------------
__global__ __launch_bounds__(256) void prep_codebook(
    const float* __restrict__ cb, _Float16* __restrict__ ehg,
    _Float16* __restrict__ elg, float* __restrict__ e2g)
{
  int tid = threadIdx.x;
  int L = tid & 63;
  int row = blockIdx.x * 4 + (tid >> 6);
  const float2* cr = (const float2*)(cb + (size_t)row * DIM);
  float2 v = cr[L];
  float s2 = v.x * v.x + v.y * v.y;
  #pragma unroll
  for (int m = 1; m < 64; m <<= 1) s2 += __shfl_xor(s2, m);
  if (L == 0) e2g[row] = -0.5f * s2;      // pre-scaled for score t = dot - e2/2
  _Float16 h0 = (_Float16)v.x, h1 = (_Float16)v.y;
  half2v hi = {h0, h1};
  half2v lo = {(_Float16)(v.x - (float)h0), (_Float16)(v.y - (float)h1)};
  ((half2v*)(ehg + (size_t)row * DIM))[L] = hi;
  ((half2v*)(elg + (size_t)row * DIM))[L] = lo;
}

// ---------------- kernel 2: LN + argmin via split-fp16 MFMA ----------------
// block = 512 (8 waves); wave handles 64 rows (4 groups of 16) -> MTILE=512.
// NSPLIT=16 -> grid 512 = 2 blocks/CU (4 waves/SIMD) so a co-resident block
// fills the MFMA pipe during this block's barriers/latency (round-4 evidence:
// 1 block/CU pinned MfmaUtil at 45% regardless of per-chunk structure).
// __launch_bounds__ 2nd arg = min BLOCKS/CU on this toolchain (round-2
// evidence); (512,2) -> 128-VGPR cap, round 4 compiled to exactly 128.
__global__ __launch_bounds__(512, 2) void argmin_kernel(
    const float* __restrict__ x, const _Float16* __restrict__ ehg,
    const _Float16* __restrict__ elg, const float* __restrict__ e2g,
    float* __restrict__ best_part, int* __restrict__ idx_part,
    float* __restrict__ x2g)
{
  // [buf][arr(hi/lo)][code n][128 halfs]; chunk kcs within a row holds global
  // chunk kc = kcs ^ (n&7)  (16B chunks). 64 KB + 2 KB e2 stage.
  __shared__ _Float16 ebuf[2][2][64][128];
  __shared__ float e2s[KCODES / NSPLIT];   // 512 floats (already -e2/2)

  int tid = threadIdx.x;
  int w   = tid >> 6;
  int L   = tid & 63;
  int c   = L & 15;      // MFMA A-row / B-col lane index
  int q   = L >> 4;      // quad

  int bx = blockIdx.x;
  int mt = bx & 31;                   // 0..31
  int ns = bx >> 5;                   // 0..15

  int rowbase = mt * MTILE + w * 64;
  int code0 = ns * (KCODES / NSPLIT);

  e2s[tid] = e2g[code0 + tid];        // 512 threads, one each

  half8 ah[4][4], al[4][4];

  #pragma unroll
  for (int g = 0; g < 4; ++g) {
    const float* xr = x + (size_t)(rowbase + g * 16 + c) * DIM;
    float v[32];
    #pragma unroll
    for (int ks = 0; ks < 4; ++ks) {
      float4 p0 = *(const float4*)(xr + ks * 32 + q * 8);
      float4 p1 = *(const float4*)(xr + ks * 32 + q * 8 + 4);
      v[ks*8+0] = p0.x; v[ks*8+1] = p0.y; v[ks*8+2] = p0.z; v[ks*8+3] = p0.w;
      v[ks*8+4] = p1.x; v[ks*8+5] = p1.y; v[ks*8+6] = p1.z; v[ks*8+7] = p1.w;
    }
    float s = 0.f;
    #pragma unroll
    for (int i = 0; i < 32; ++i) s += v[i];
    s += __shfl_xor(s, 16); s += __shfl_xor(s, 32);
    float mu = s * (1.0f / 128.0f);
    float s2 = 0.f;
    #pragma unroll
    for (int i = 0; i < 32; ++i) { float d = v[i] - mu; s2 += d * d; }
    s2 += __shfl_xor(s2, 16); s2 += __shfl_xor(s2, 32);
    float rstd = 1.0f / sqrtf(s2 * (1.0f / 128.0f) + 1e-5f);
    float x2 = 0.f;
    #pragma unroll
    for (int ks = 0; ks < 4; ++ks)
      #pragma unroll
      for (int j = 0; j < 8; ++j) {
        float xv = (v[ks*8+j] - mu) * rstd;
        x2 += xv * xv;
        _Float16 h = (_Float16)xv;
        ah[g][ks][j] = h;
        al[g][ks][j] = (_Float16)(xv - (float)h);
      }
    x2 += __shfl_xor(x2, 16); x2 += __shfl_xor(x2, 32);
    // ||xn||^2 per row, needed for loss = x2 - 2*t_best; one split writes it
    if (ns == 0 && q == 0) x2g[rowbase + g * 16 + c] = x2;
  }

  // track t = dot - e2/2 (maximize); ties -> smaller index
  float best[4][4]; int bidx[4][4];
  #pragma unroll
  for (int g = 0; g < 4; ++g)
    #pragma unroll
    for (int r = 0; r < 4; ++r) { best[g][r] = -3.4e38f; bidx[g][r] = 0; }

  _Float16* lbase = &ebuf[0][0][0][0];

  // ---- async staging: 2048 16B chunks per tile, 4 per thread ----
  auto stage = [&](int ch, int p) {
    int cbase = code0 + ch * NT;
    _Float16* lb = lbase + (size_t)p * 2 * 64 * 128;
    #pragma unroll
    for (int it = 0; it < 4; ++it) {
      int cid = it * 512 + tid;          // 0..2047
      int arr = cid >> 10;               // 0 = hi, 1 = lo
      int lc  = cid & 1023;
      int n   = lc >> 4;
      int kcs = lc & 15;                 // LDS slot chunk
      int kc  = kcs ^ (n & 7);           // global chunk (inverse swizzle)
      const _Float16* g = (arr ? elg : ehg) + (size_t)(cbase + n) * DIM + kc * 8;
      async_copy16(g, lb + (size_t)cid * 8);
    }
  };

  stage(0, 0);
  __syncthreads();

  for (int ch = 0; ch < NCHUNK; ++ch) {
    int p = ch & 1;
    int cbase = code0 + ch * NT;
    if (ch + 1 < NCHUNK) stage(ch + 1, p ^ 1);

    float e2h[4];
    #pragma unroll
    for (int s = 0; s < 4; ++s) e2h[s] = e2s[ch * NT + s * 16 + c];

    #pragma unroll
    for (int s = 0; s < 4; ++s) {
      int n = s * 16 + c;                // n & 7 == c & 7
      half8 bh[4], bl[4];
      #pragma unroll
      for (int ks = 0; ks < 4; ++ks) {
        int slot = ((ks * 4 + q) ^ (c & 7)) * 8;
        bh[ks] = *(const half8*)&ebuf[p][0][n][slot];
        bl[ks] = *(const half8*)&ebuf[p][1][n][slot];
      }
      int nn = cbase + n;
      #pragma unroll
      for (int g = 0; g < 4; ++g) {
        floatx4 acc = {e2h[s], e2h[s], e2h[s], e2h[s]};
        #pragma unroll
        for (int ks = 0; ks < 4; ++ks) {
          acc = __builtin_amdgcn_mfma_f32_16x16x32_f16(ah[g][ks], bh[ks], acc, 0, 0, 0);
          acc = __builtin_amdgcn_mfma_f32_16x16x32_f16(ah[g][ks], bl[ks], acc, 0, 0, 0);
          acc = __builtin_amdgcn_mfma_f32_16x16x32_f16(al[g][ks], bh[ks], acc, 0, 0, 0);
        }
        #pragma unroll
        for (int r = 0; r < 4; ++r) {
          float t = acc[r];
          if (t > best[g][r]) { best[g][r] = t; bidx[g][r] = nn; }
        }
      }
    }
    __syncthreads();   // drains async stage of ch+1; protects buf reuse
  }

  // reduce over the 16 col-lanes of each quad; max-t, ties -> smaller index
  #pragma unroll
  for (int m = 1; m < 16; m <<= 1)
    #pragma unroll
    for (int g = 0; g < 4; ++g)
      #pragma unroll
      for (int r = 0; r < 4; ++r) {
        float ob = __shfl_xor(best[g][r], m);
        int   oi = __shfl_xor(bidx[g][r], m);
        if (ob > best[g][r] || (ob == best[g][r] && oi < bidx[g][r])) {
          best[g][r] = ob; bidx[g][r] = oi;
        }
      }
  if (c == 0) {
    #pragma unroll
    for (int g = 0; g < 4; ++g)
      #pragma unroll
      for (int r = 0; r < 4; ++r) {
        int row = rowbase + g * 16 + q * 4 + r;
        best_part[(size_t)row * NSPLIT + ns] = best[g][r];
        idx_part [(size_t)row * NSPLIT + ns] = bidx[g][r];
      }
  }
}

// ---------------- kernel 3: merge + gather + loss (from score) ----------------
// 32 rows/block. loss per row = ||xn||^2 - 2*t_best (t = dot - e2/2).
__global__ __launch_bounds__(256) void gather_loss_kernel(
    const float* __restrict__ cb, const float* __restrict__ best_part,
    const int* __restrict__ idx_part, const float* __restrict__ x2g,
    float* __restrict__ out_q, float* __restrict__ out_ind,
    float* __restrict__ out_loss)
{
  __shared__ int   sidx[32];
  __shared__ float sloss[32];
  int tid = threadIdx.x;
  int rb = blockIdx.x * 32;
  int r = tid >> 3, k = tid & 7;
  int row = rb + r;

  float b  = best_part[(size_t)row * NSPLIT + k];
  int   bi = idx_part [(size_t)row * NSPLIT + k];
  float b2 = best_part[(size_t)row * NSPLIT + 8 + k];
  int   bj = idx_part [(size_t)row * NSPLIT + 8 + k];
  if (b2 > b || (b2 == b && bj < bi)) { b = b2; bi = bj; }
  #pragma unroll
  for (int m = 1; m < 8; m <<= 1) {
    float ob = __shfl_xor(b, m);
    int   oi = __shfl_xor(bi, m);
    if (ob > b || (ob == b && oi < bi)) { b = ob; bi = oi; }
  }
  if (k == 0) {
    sidx[r] = bi;
    out_ind[row] = (float)bi;
    sloss[r] = x2g[row] - 2.0f * b;
  }
  __syncthreads();

  if (tid < 32) {
    float s = sloss[tid];
    #pragma unroll
    for (int m = 1; m < 32; m <<= 1) s += __shfl_xor(s, m);
    if (tid == 0) atomicAdd(out_loss, s * LOSS_SCALE);
  }

  // copy 32 codebook rows (512B each) to out_q
  const float4* cb4 = (const float4*)cb;
  float4* oq4 = (float4*)out_q;
  #pragma unroll
  for (int it = 0; it < 4; ++it) {
    int idx = it * 256 + tid;          // 0..1023
    int r2 = idx >> 5, c4 = idx & 31;
    oq4[(size_t)(rb + r2) * 32 + c4] = cb4[(size_t)sidx[r2] * 32 + c4];
  }
}

extern "C" void kernel_launch(void* const* d_in, const int* in_sizes, int n_in,
                              void* d_out, int out_size, void* d_ws, size_t ws_size,
                              hipStream_t stream)
{
  const float* x  = (const float*)d_in[0];   // [4,4096,128] fp32
  const float* cb = (const float*)d_in[1];   // [8192,128]  fp32

  char* ws = (char*)d_ws;
  _Float16* ehg      = (_Float16*)(ws + 0);          // 2 MB
  _Float16* elg      = (_Float16*)(ws + 2097152);    // 2 MB
  float*    e2g      = (float*)   (ws + 4194304);    // 32 KB
  float*    best_part= (float*)   (ws + 4227072);    // 1 MB
  int*      idx_part = (int*)     (ws + 5275648);    // 1 MB
  float*    x2g      = (float*)   (ws + 6324224);    // 64 KB

  float* out_q    = (float*)d_out;                   // 16384*128
  float* out_ind  = out_q + (size_t)ROWS * DIM;      // 16384 (as float)
  float* out_loss = out_ind + ROWS;                  // 1

  hipMemsetAsync(out_loss, 0, sizeof(float), stream);
  prep_codebook<<<KCODES / 4, 256, 0, stream>>>(cb, ehg, elg, e2g);
  argmin_kernel<<<(ROWS / MTILE) * NSPLIT, 512, 0, stream>>>(x, ehg, elg, e2g, best_part, idx_part, x2g);
  gather_loss_kernel<<<ROWS / 32, 256, 0, stream>>>(cb, best_part, idx_part, x2g, out_q, out_ind, out_loss);
}